// Round 1
// baseline (4998.945 us; speedup 1.0000x reference)
//
#include <hip/hip_runtime.h>
#include <math.h>

#define S_ 1024
#define D_ 256

__device__ __forceinline__ float wave_sum64(float x) {
    x += __shfl_xor(x, 32); x += __shfl_xor(x, 16); x += __shfl_xor(x, 8);
    x += __shfl_xor(x, 4);  x += __shfl_xor(x, 2);  x += __shfl_xor(x, 1);
    return x;
}

// ---------------- embed + LN (1 block = 1 token, 64 threads) ----------------
__global__ __launch_bounds__(64) void embed_ln_kernel(
    const int* __restrict__ ids, const float* __restrict__ tok,
    const float* __restrict__ pos, const float* __restrict__ w,
    const float* __restrict__ b, float* __restrict__ X)
{
    const int tokid = blockIdx.x;          // b*S + s
    const int s = tokid & (S_ - 1);
    const int t = threadIdx.x;
    const int id = ids[tokid];
    float4 e = *(const float4*)&tok[id * D_ + t * 4];
    float4 p = *(const float4*)&pos[s * D_ + t * 4];
    float4 x = make_float4(e.x + p.x, e.y + p.y, e.z + p.z, e.w + p.w);
    float sum = x.x + x.y + x.z + x.w;
    float sq  = x.x * x.x + x.y * x.y + x.z * x.z + x.w * x.w;
    sum = wave_sum64(sum); sq = wave_sum64(sq);
    float mean = sum * (1.f / D_);
    float var  = sq * (1.f / D_) - mean * mean;
    float rs   = rsqrtf(var + 1e-5f);
    float4 wv = *(const float4*)&w[t * 4];
    float4 bv = *(const float4*)&b[t * 4];
    float4 o = make_float4((x.x - mean) * rs * wv.x + bv.x,
                           (x.y - mean) * rs * wv.y + bv.y,
                           (x.z - mean) * rs * wv.z + bv.z,
                           (x.w - mean) * rs * wv.w + bv.w);
    *(float4*)&X[(size_t)tokid * D_ + t * 4] = o;
}

// ---------------- residual add + LN ----------------
__global__ __launch_bounds__(64) void ln_res_kernel(
    const float* __restrict__ Y, const float* __restrict__ R,
    const float* __restrict__ w, const float* __restrict__ b,
    float* __restrict__ T)
{
    const int tokid = blockIdx.x;
    const int t = threadIdx.x;
    const size_t base = (size_t)tokid * D_ + t * 4;
    float4 y = *(const float4*)&Y[base];
    float4 r = *(const float4*)&R[base];
    float4 x = make_float4(y.x + r.x, y.y + r.y, y.z + r.z, y.w + r.w);
    float sum = x.x + x.y + x.z + x.w;
    float sq  = x.x * x.x + x.y * x.y + x.z * x.z + x.w * x.w;
    sum = wave_sum64(sum); sq = wave_sum64(sq);
    float mean = sum * (1.f / D_);
    float var  = sq * (1.f / D_) - mean * mean;
    float rs   = rsqrtf(var + 1e-5f);
    float4 wv = *(const float4*)&w[t * 4];
    float4 bv = *(const float4*)&b[t * 4];
    float4 o = make_float4((x.x - mean) * rs * wv.x + bv.x,
                           (x.y - mean) * rs * wv.y + bv.y,
                           (x.z - mean) * rs * wv.z + bv.z,
                           (x.w - mean) * rs * wv.w + bv.w);
    *(float4*)&T[base] = o;
}

// ---------------- generic tiled f32 GEMM: C = A(MxK) @ W(KxN) + bias ----------------
// BM = TM*16, BN = 64, BK = 16, 256 threads, thread computes TM x 4.
template<int TM, int RELU>
__device__ __forceinline__ void gemm_core(
    float* Asl, float* Wsl,
    const float* __restrict__ A, const float* __restrict__ W,
    const float* __restrict__ bias, float* __restrict__ C,
    int N, int K, int m0, int n0)
{
    const int BM = TM * 16;
    float (*As)[BM] = (float (*)[BM])Asl;   // [16][BM] k-major
    float (*Ws)[64] = (float (*)[64])Wsl;   // [16][64]
    const int t  = threadIdx.x;
    const int tn = t & 15;
    const int tm = t >> 4;
    float acc[TM][4] = {};
    for (int k0 = 0; k0 < K; k0 += 16) {
        #pragma unroll
        for (int j = 0; j < BM / 64; ++j) {
            int idx = t + j * 256;
            int row = idx >> 2;
            int cg  = (idx & 3) * 4;
            float4 av = *(const float4*)&A[(m0 + row) * K + k0 + cg];
            As[cg + 0][row] = av.x; As[cg + 1][row] = av.y;
            As[cg + 2][row] = av.z; As[cg + 3][row] = av.w;
        }
        {
            int kk = t >> 4;
            int cg = (t & 15) * 4;
            *(float4*)&Ws[kk][cg] = *(const float4*)&W[(k0 + kk) * N + n0 + cg];
        }
        __syncthreads();
        #pragma unroll
        for (int kk = 0; kk < 16; ++kk) {
            float a[TM], bb[4];
            #pragma unroll
            for (int i = 0; i < TM / 4; ++i)
                *(float4*)&a[i * 4] = *(const float4*)&As[kk][tm * TM + i * 4];
            *(float4*)&bb[0] = *(const float4*)&Ws[kk][tn * 4];
            #pragma unroll
            for (int i = 0; i < TM; ++i)
                #pragma unroll
                for (int j = 0; j < 4; ++j)
                    acc[i][j] = fmaf(a[i], bb[j], acc[i][j]);
        }
        __syncthreads();
    }
    float4 bv = *(const float4*)&bias[n0 + tn * 4];
    #pragma unroll
    for (int i = 0; i < TM; ++i) {
        float4 o = make_float4(acc[i][0] + bv.x, acc[i][1] + bv.y,
                               acc[i][2] + bv.z, acc[i][3] + bv.w);
        if (RELU) {
            o.x = fmaxf(o.x, 0.f); o.y = fmaxf(o.y, 0.f);
            o.z = fmaxf(o.z, 0.f); o.w = fmaxf(o.w, 0.f);
        }
        *(float4*)&C[(m0 + tm * TM + i) * N + n0 + tn * 4] = o;
    }
}

template<int TM, int RELU>
__global__ __launch_bounds__(256) void gemm_kernel(
    const float* __restrict__ A, const float* __restrict__ W,
    const float* __restrict__ bias, float* __restrict__ C, int N, int K)
{
    __shared__ float As[16 * TM * 16];
    __shared__ float Ws[16 * 64];
    gemm_core<TM, RELU>(As, Ws, A, W, bias, C, N, K,
                        blockIdx.x * TM * 16, blockIdx.y * 64);
}

// fused Q/K/V projection: grid.y in [0,12): sel = y>>2 picks matrix, (y&3)*64 is n0
__global__ __launch_bounds__(256) void gemm_qkv_kernel(
    const float* __restrict__ A,
    const float* __restrict__ Wq, const float* __restrict__ Wk, const float* __restrict__ Wv,
    const float* __restrict__ bq, const float* __restrict__ bk, const float* __restrict__ bv,
    float* __restrict__ q, float* __restrict__ k, float* __restrict__ v)
{
    __shared__ float As[16 * 128];
    __shared__ float Ws[16 * 64];
    const int sel = blockIdx.y >> 2;
    const int n0 = (blockIdx.y & 3) * 64;
    const float* W    = sel == 0 ? Wq : (sel == 1 ? Wk : Wv);
    const float* bias = sel == 0 ? bq : (sel == 1 ? bk : bv);
    float* C          = sel == 0 ? q  : (sel == 1 ? k  : v);
    gemm_core<8, 0>(As, Ws, A, W, bias, C, 256, 256, blockIdx.x * 128, n0);
}

// ---------------- flash attention, f32; 64 queries/block, KV tiles of 64 ----------------
__global__ __launch_bounds__(256) void attn_kernel(
    const float* __restrict__ q, const float* __restrict__ k,
    const float* __restrict__ v, const int* __restrict__ ids,
    float* __restrict__ ctx)
{
    __shared__ float Ks[64][32];
    __shared__ float Vs[64][32];
    __shared__ float maskn[64];
    const int bh = blockIdx.x;         // 0..63
    const int b = bh >> 3, h = bh & 7;
    const int q0 = blockIdx.y * 64;
    const int t = threadIdx.x;
    const int r = t >> 2, qt = t & 3;  // row 0..63, quarter 0..3
    const float scale = 0.17677669529663687f;  // 1/sqrt(32)

    float4 qv[8];
    const float* qrow = q + (b * S_ + q0 + r) * D_ + h * 32;
    #pragma unroll
    for (int d4 = 0; d4 < 8; ++d4) qv[d4] = *(const float4*)&qrow[d4 * 4];

    float m = -INFINITY, l = 0.f;
    float4 oacc[8] = {};

    for (int kt = 0; kt < 16; ++kt) {
        const int k0 = kt * 64;
        #pragma unroll
        for (int j = 0; j < 2; ++j) {
            int idx = t + j * 256;       // 0..511
            int row = idx >> 3;          // 0..63
            int cg  = (idx & 7) * 4;     // 0..28
            int base = (b * S_ + k0 + row) * D_ + h * 32 + cg;
            *(float4*)&Ks[row][cg] = *(const float4*)&k[base];
            *(float4*)&Vs[row][cg] = *(const float4*)&v[base];
        }
        if (t < 64) maskn[t] = (ids[b * S_ + k0 + t] == 0) ? 1.f : 0.f;
        __syncthreads();

        float sarr[16];
        float tmax = -INFINITY;
        #pragma unroll
        for (int i = 0; i < 16; ++i) {
            int c = qt * 16 + i;
            float4 a = make_float4(0.f, 0.f, 0.f, 0.f);
            #pragma unroll
            for (int d4 = 0; d4 < 8; ++d4) {
                float4 kv4 = *(const float4*)&Ks[c][d4 * 4];
                a.x = fmaf(qv[d4].x, kv4.x, a.x);
                a.y = fmaf(qv[d4].y, kv4.y, a.y);
                a.z = fmaf(qv[d4].z, kv4.z, a.z);
                a.w = fmaf(qv[d4].w, kv4.w, a.w);
            }
            float sc = ((a.x + a.y) + (a.z + a.w)) * scale;
            sc = (maskn[c] != 0.f) ? -1e9f : sc;
            sarr[i] = sc;
            tmax = fmaxf(tmax, sc);
        }
        tmax = fmaxf(tmax, __shfl_xor(tmax, 1));
        tmax = fmaxf(tmax, __shfl_xor(tmax, 2));
        float mn = fmaxf(m, tmax);
        float factor = __expf(m - mn);    // m=-inf first iter -> 0, fine
        float psum = 0.f;
        #pragma unroll
        for (int i = 0; i < 16; ++i) {
            float p = __expf(sarr[i] - mn);
            sarr[i] = p;
            psum += p;
        }
        psum += __shfl_xor(psum, 1);
        psum += __shfl_xor(psum, 2);
        l = l * factor + psum;
        m = mn;
        #pragma unroll
        for (int d4 = 0; d4 < 8; ++d4) {
            oacc[d4].x *= factor; oacc[d4].y *= factor;
            oacc[d4].z *= factor; oacc[d4].w *= factor;
        }
        #pragma unroll
        for (int i = 0; i < 16; ++i) {
            int c = qt * 16 + i;
            float p = sarr[i];
            #pragma unroll
            for (int d4 = 0; d4 < 8; ++d4) {
                float4 vv = *(const float4*)&Vs[c][d4 * 4];
                oacc[d4].x = fmaf(p, vv.x, oacc[d4].x);
                oacc[d4].y = fmaf(p, vv.y, oacc[d4].y);
                oacc[d4].z = fmaf(p, vv.z, oacc[d4].z);
                oacc[d4].w = fmaf(p, vv.w, oacc[d4].w);
            }
        }
        __syncthreads();
    }
    // sum partials across the 4 lanes of this query row
    #pragma unroll
    for (int d4 = 0; d4 < 8; ++d4) {
        oacc[d4].x += __shfl_xor(oacc[d4].x, 1); oacc[d4].x += __shfl_xor(oacc[d4].x, 2);
        oacc[d4].y += __shfl_xor(oacc[d4].y, 1); oacc[d4].y += __shfl_xor(oacc[d4].y, 2);
        oacc[d4].z += __shfl_xor(oacc[d4].z, 1); oacc[d4].z += __shfl_xor(oacc[d4].z, 2);
        oacc[d4].w += __shfl_xor(oacc[d4].w, 1); oacc[d4].w += __shfl_xor(oacc[d4].w, 2);
    }
    const float invl = 1.f / l;
    float* crow = ctx + (b * S_ + q0 + r) * D_ + h * 32;
    #pragma unroll
    for (int j = 0; j < 2; ++j) {
        int d4 = qt * 2 + j;
        float4 ov = oacc[d4];
        ov.x *= invl; ov.y *= invl; ov.z *= invl; ov.w *= invl;
        *(float4*)&crow[d4 * 4] = ov;
    }
}

// ---------------- classifier head (tiny; one block) ----------------
__global__ __launch_bounds__(256) void head_kernel(
    const float* __restrict__ X,
    const float* __restrict__ ft1w, const float* __restrict__ ft1b,
    const float* __restrict__ ft2w, const float* __restrict__ ft2b,
    const float* __restrict__ clw,  const float* __restrict__ clb,
    float* __restrict__ out)
{
    __shared__ float clsS[8][256];
    __shared__ float h1S[8][256];
    __shared__ float featS[8][128];
    const int t = threadIdx.x;
    #pragma unroll
    for (int j = 0; j < 8; ++j) {
        int idx = t + j * 256;
        int b = idx >> 8, d = idx & 255;
        clsS[b][d] = X[(size_t)b * S_ * D_ + d];
    }
    __syncthreads();
    {
        float s[8] = {};
        for (int d = 0; d < 256; ++d) {
            float w = ft1w[d * 256 + t];
            #pragma unroll
            for (int b = 0; b < 8; ++b) s[b] = fmaf(clsS[b][d], w, s[b]);
        }
        float bias = ft1b[t];
        #pragma unroll
        for (int b = 0; b < 8; ++b) h1S[b][t] = fmaxf(s[b] + bias, 0.f);
    }
    __syncthreads();
    #pragma unroll
    for (int j = 0; j < 4; ++j) {
        int idx = t + j * 256;           // 0..1023 = b*128 + c
        int b = idx >> 7, c = idx & 127;
        float s = 0.f;
        for (int d = 0; d < 256; ++d) s = fmaf(h1S[b][d], ft2w[d * 128 + c], s);
        s += ft2b[c];
        featS[b][c] = s;
        out[16 + idx] = s;
    }
    __syncthreads();
    if (t < 16) {
        int b = t >> 1, c = t & 1;
        float s = 0.f;
        for (int d = 0; d < 128; ++d) s = fmaf(featS[b][d], clw[d * 2 + c], s);
        out[t] = s + clb[c];
    }
}

extern "C" void kernel_launch(void* const* d_in, const int* in_sizes, int n_in,
                              void* d_out, int out_size, void* d_ws, size_t ws_size,
                              hipStream_t stream)
{
    const int*   ids  = (const int*)d_in[0];
    const float* tok  = (const float*)d_in[1];
    const float* pos  = (const float*)d_in[2];
    const float* elnw = (const float*)d_in[3];
    const float* elnb = (const float*)d_in[4];
    const float* Wq   = (const float*)d_in[5];
    const float* bq   = (const float*)d_in[6];
    const float* Wk   = (const float*)d_in[7];
    const float* bk   = (const float*)d_in[8];
    const float* Wv   = (const float*)d_in[9];
    const float* bv   = (const float*)d_in[10];
    const float* Wo   = (const float*)d_in[11];
    const float* bo   = (const float*)d_in[12];
    const float* lnw  = (const float*)d_in[13];
    const float* lnb  = (const float*)d_in[14];
    const float* W1   = (const float*)d_in[15];
    const float* b1   = (const float*)d_in[16];
    const float* W2   = (const float*)d_in[17];
    const float* b2   = (const float*)d_in[18];
    const float* ft1w = (const float*)d_in[19];
    const float* ft1b = (const float*)d_in[20];
    const float* ft2w = (const float*)d_in[21];
    const float* ft2b = (const float*)d_in[22];
    const float* clw  = (const float*)d_in[23];
    const float* clb  = (const float*)d_in[24];
    float* out = (float*)d_out;

    char* ws = (char*)d_ws;
    const size_t SZ = (size_t)8192 * 256 * 4;       // one (B*S, D) f32 buffer
    float* X   = (float*)(ws + 0 * SZ);
    float* Y   = (float*)(ws + 1 * SZ);
    float* T   = (float*)(ws + 2 * SZ);
    float* q   = (float*)(ws + 3 * SZ);
    float* k   = (float*)(ws + 4 * SZ);
    float* v   = (float*)(ws + 5 * SZ);
    float* ctx = (float*)(ws + 6 * SZ);
    float* Hb  = (float*)(ws + 3 * SZ);             // 33.5MB, overlaps dead q/k/v/ctx

    embed_ln_kernel<<<8192, 64, 0, stream>>>(ids, tok, pos, elnw, elnb, X);

    for (int i = 0; i < 4; ++i) {
        const float* Wq_i = Wq + i * 65536;  const float* bq_i = bq + i * 256;
        const float* Wk_i = Wk + i * 65536;  const float* bk_i = bk + i * 256;
        const float* Wv_i = Wv + i * 65536;  const float* bv_i = bv + i * 256;
        const float* Wo_i = Wo + i * 65536;  const float* bo_i = bo + i * 256;

        gemm_qkv_kernel<<<dim3(64, 12), 256, 0, stream>>>(
            X, Wq_i, Wk_i, Wv_i, bq_i, bk_i, bv_i, q, k, v);
        attn_kernel<<<dim3(64, 16), 256, 0, stream>>>(q, k, v, ids, ctx);
        gemm_kernel<4, 0><<<dim3(128, 4), 256, 0, stream>>>(ctx, Wo_i, bo_i, Y, 256, 256);
        ln_res_kernel<<<8192, 64, 0, stream>>>(Y, X, lnw + i * 256, lnb + i * 256, T);
        gemm_kernel<8, 1><<<dim3(64, 16), 256, 0, stream>>>(T, W1 + i * 262144, b1 + i * 1024, Hb, 1024, 256);
        gemm_kernel<4, 0><<<dim3(128, 4), 256, 0, stream>>>(Hb, W2 + i * 262144, b2 + i * 256, X, 256, 1024);
    }

    head_kernel<<<1, 256, 0, stream>>>(X, ft1w, ft1b, ft2w, ft2b, clw, clb, out);
}

// Round 2
// 1071.088 us; speedup vs baseline: 4.6672x; 4.6672x over previous
//
#include <hip/hip_runtime.h>
#include <hip/hip_bf16.h>
#include <math.h>

#define S_ 1024
#define D_ 256

typedef __attribute__((ext_vector_type(8))) short short8;
typedef __attribute__((ext_vector_type(4))) float f32x4;
typedef __attribute__((ext_vector_type(4))) unsigned int u32x4;

__device__ __forceinline__ float wave_sum64(float x) {
    x += __shfl_xor(x, 32); x += __shfl_xor(x, 16); x += __shfl_xor(x, 8);
    x += __shfl_xor(x, 4);  x += __shfl_xor(x, 2);  x += __shfl_xor(x, 1);
    return x;
}

__device__ __forceinline__ unsigned short f2bf(float x) {
    return __builtin_bit_cast(unsigned short, __float2bfloat16(x));
}
__device__ __forceinline__ unsigned int pk2(float lo, float hi) {
    return (unsigned int)f2bf(lo) | ((unsigned int)f2bf(hi) << 16);
}
__device__ __forceinline__ short8 load_bf8(const float* p) {
    float4 a = *(const float4*)p;
    float4 b = *(const float4*)(p + 4);
    short8 r;
    r[0] = (short)f2bf(a.x); r[1] = (short)f2bf(a.y);
    r[2] = (short)f2bf(a.z); r[3] = (short)f2bf(a.w);
    r[4] = (short)f2bf(b.x); r[5] = (short)f2bf(b.y);
    r[6] = (short)f2bf(b.z); r[7] = (short)f2bf(b.w);
    return r;
}

// ---------------- embed + LN (1 block = 1 token, 64 threads) ----------------
__global__ __launch_bounds__(64) void embed_ln_kernel(
    const int* __restrict__ ids, const float* __restrict__ tok,
    const float* __restrict__ pos, const float* __restrict__ w,
    const float* __restrict__ b, float* __restrict__ X)
{
    const int tokid = blockIdx.x;          // b*S + s
    const int s = tokid & (S_ - 1);
    const int t = threadIdx.x;
    const int id = ids[tokid];
    float4 e = *(const float4*)&tok[id * D_ + t * 4];
    float4 p = *(const float4*)&pos[s * D_ + t * 4];
    float4 x = make_float4(e.x + p.x, e.y + p.y, e.z + p.z, e.w + p.w);
    float sum = x.x + x.y + x.z + x.w;
    float sq  = x.x * x.x + x.y * x.y + x.z * x.z + x.w * x.w;
    sum = wave_sum64(sum); sq = wave_sum64(sq);
    float mean = sum * (1.f / D_);
    float var  = sq * (1.f / D_) - mean * mean;
    float rs   = rsqrtf(var + 1e-5f);
    float4 wv = *(const float4*)&w[t * 4];
    float4 bv = *(const float4*)&b[t * 4];
    float4 o = make_float4((x.x - mean) * rs * wv.x + bv.x,
                           (x.y - mean) * rs * wv.y + bv.y,
                           (x.z - mean) * rs * wv.z + bv.z,
                           (x.w - mean) * rs * wv.w + bv.w);
    *(float4*)&X[(size_t)tokid * D_ + t * 4] = o;
}

// ---------------- residual add + LN ----------------
__global__ __launch_bounds__(64) void ln_res_kernel(
    const float* __restrict__ Y, const float* __restrict__ R,
    const float* __restrict__ w, const float* __restrict__ b,
    float* __restrict__ T)
{
    const int tokid = blockIdx.x;
    const int t = threadIdx.x;
    const size_t base = (size_t)tokid * D_ + t * 4;
    float4 y = *(const float4*)&Y[base];
    float4 r = *(const float4*)&R[base];
    float4 x = make_float4(y.x + r.x, y.y + r.y, y.z + r.z, y.w + r.w);
    float sum = x.x + x.y + x.z + x.w;
    float sq  = x.x * x.x + x.y * x.y + x.z * x.z + x.w * x.w;
    sum = wave_sum64(sum); sq = wave_sum64(sq);
    float mean = sum * (1.f / D_);
    float var  = sq * (1.f / D_) - mean * mean;
    float rs   = rsqrtf(var + 1e-5f);
    float4 wv = *(const float4*)&w[t * 4];
    float4 bv = *(const float4*)&b[t * 4];
    float4 o = make_float4((x.x - mean) * rs * wv.x + bv.x,
                           (x.y - mean) * rs * wv.y + bv.y,
                           (x.z - mean) * rs * wv.z + bv.z,
                           (x.w - mean) * rs * wv.w + bv.w);
    *(float4*)&T[base] = o;
}

// ---------------- generic tiled f32 GEMM: C = A(MxK) @ W(KxN) + bias ----------------
template<int TM, int RELU>
__device__ __forceinline__ void gemm_core(
    float* Asl, float* Wsl,
    const float* __restrict__ A, const float* __restrict__ W,
    const float* __restrict__ bias, float* __restrict__ C,
    int N, int K, int m0, int n0)
{
    const int BM = TM * 16;
    float (*As)[BM] = (float (*)[BM])Asl;   // [16][BM] k-major
    float (*Ws)[64] = (float (*)[64])Wsl;   // [16][64]
    const int t  = threadIdx.x;
    const int tn = t & 15;
    const int tm = t >> 4;
    float acc[TM][4] = {};
    for (int k0 = 0; k0 < K; k0 += 16) {
        #pragma unroll
        for (int j = 0; j < BM / 64; ++j) {
            int idx = t + j * 256;
            int row = idx >> 2;
            int cg  = (idx & 3) * 4;
            float4 av = *(const float4*)&A[(m0 + row) * K + k0 + cg];
            As[cg + 0][row] = av.x; As[cg + 1][row] = av.y;
            As[cg + 2][row] = av.z; As[cg + 3][row] = av.w;
        }
        {
            int kk = t >> 4;
            int cg = (t & 15) * 4;
            *(float4*)&Ws[kk][cg] = *(const float4*)&W[(k0 + kk) * N + n0 + cg];
        }
        __syncthreads();
        #pragma unroll
        for (int kk = 0; kk < 16; ++kk) {
            float a[TM], bb[4];
            #pragma unroll
            for (int i = 0; i < TM / 4; ++i)
                *(float4*)&a[i * 4] = *(const float4*)&As[kk][tm * TM + i * 4];
            *(float4*)&bb[0] = *(const float4*)&Ws[kk][tn * 4];
            #pragma unroll
            for (int i = 0; i < TM; ++i)
                #pragma unroll
                for (int j = 0; j < 4; ++j)
                    acc[i][j] = fmaf(a[i], bb[j], acc[i][j]);
        }
        __syncthreads();
    }
    float4 bv = *(const float4*)&bias[n0 + tn * 4];
    #pragma unroll
    for (int i = 0; i < TM; ++i) {
        float4 o = make_float4(acc[i][0] + bv.x, acc[i][1] + bv.y,
                               acc[i][2] + bv.z, acc[i][3] + bv.w);
        if (RELU) {
            o.x = fmaxf(o.x, 0.f); o.y = fmaxf(o.y, 0.f);
            o.z = fmaxf(o.z, 0.f); o.w = fmaxf(o.w, 0.f);
        }
        *(float4*)&C[(m0 + tm * TM + i) * N + n0 + tn * 4] = o;
    }
}

template<int TM, int RELU>
__global__ __launch_bounds__(256) void gemm_kernel(
    const float* __restrict__ A, const float* __restrict__ W,
    const float* __restrict__ bias, float* __restrict__ C, int N, int K)
{
    __shared__ float As[16 * TM * 16];
    __shared__ float Ws[16 * 64];
    gemm_core<TM, RELU>(As, Ws, A, W, bias, C, N, K,
                        blockIdx.x * TM * 16, blockIdx.y * 64);
}

// fused Q/K/V projection
__global__ __launch_bounds__(256) void gemm_qkv_kernel(
    const float* __restrict__ A,
    const float* __restrict__ Wq, const float* __restrict__ Wk, const float* __restrict__ Wv,
    const float* __restrict__ bq, const float* __restrict__ bk, const float* __restrict__ bv,
    float* __restrict__ q, float* __restrict__ k, float* __restrict__ v)
{
    __shared__ float As[16 * 128];
    __shared__ float Ws[16 * 64];
    const int sel = blockIdx.y >> 2;
    const int n0 = (blockIdx.y & 3) * 64;
    const float* W    = sel == 0 ? Wq : (sel == 1 ? Wk : Wv);
    const float* bias = sel == 0 ? bq : (sel == 1 ? bk : bv);
    float* C          = sel == 0 ? q  : (sel == 1 ? k  : v);
    gemm_core<8, 0>(As, Ws, A, W, bias, C, 256, 256, blockIdx.x * 128, n0);
}

// ---------------- MFMA bf16 flash attention ----------------
// Block: 256 thr (4 waves), one (b,h), 64 queries (wave w owns 16).
// Swapped form: S^T[k][q] = mfma(A=K-frag, B=Q-frag); softmax state lane-local;
// ctx^T[v][q] = mfma(A=V-frag(LDS bf16-pairs), B=P^T-frag(shuffled)).
__global__ __launch_bounds__(256, 4) void attn_mfma_kernel(
    const float* __restrict__ q, const float* __restrict__ k,
    const float* __restrict__ v, const int* __restrict__ ids,
    float* __restrict__ ctxo)
{
    __shared__ unsigned int Vp[32 * 36];   // V bf16 pairs: row kp=(k/2), col v; pad 36 -> <=2-way
    __shared__ float maskn[64];
    const int t = threadIdx.x;
    const int bh = blockIdx.x, b = bh >> 3, h = bh & 7;
    const int q0 = blockIdx.y * 64;
    const int wid = t >> 6;
    const int lane = t & 63;
    const int i = lane & 15;      // q-col (and A-row for V)
    const int g = lane >> 4;      // k-chunk group
    const int kp = t >> 3;        // staging: row-pair 0..31
    const int v0s = (t & 7) * 4;  // staging: col group

    const size_t bS = (size_t)b * S_;
    const float scale = 0.17677669529663687f;   // 1/sqrt(32)

    // Q fragment (B operand): lane holds Q[q0+wid*16+i][h*32 + 8g + j]
    const short8 qf = load_bf8(q + (bS + q0 + wid * 16 + i) * D_ + h * 32 + g * 8);

    float m = -INFINITY, l = 0.f;
    f32x4 cacc[2];
    f32x4 zf = {0.f, 0.f, 0.f, 0.f};
    cacc[0] = zf; cacc[1] = zf;

    const float* kbase = k + (bS + i) * D_ + h * 32 + g * 8;
    const float* vbase = v + (bS + 2 * kp) * D_ + h * 32 + v0s;

    for (int kt = 0; kt < 16; ++kt) {
        const int k0 = kt * 64;
        // ---- stage V bf16-pairs + mask addends ----
        {
            const float* vb = vbase + (size_t)k0 * D_;
            float4 a0 = *(const float4*)vb;
            float4 a1 = *(const float4*)(vb + D_);
            u32x4 wv;
            wv[0] = pk2(a0.x, a1.x); wv[1] = pk2(a0.y, a1.y);
            wv[2] = pk2(a0.z, a1.z); wv[3] = pk2(a0.w, a1.w);
            *(u32x4*)&Vp[kp * 36 + v0s] = wv;
            if (t < 64) maskn[t] = (ids[bS + k0 + t] == 0) ? -1e9f : 0.f;
        }
        // ---- K fragments + S^T MFMAs (no LDS dependency) ----
        short8 kf[4];
        const float* kb = kbase + (size_t)k0 * D_;
        #pragma unroll
        for (int c = 0; c < 4; ++c) kf[c] = load_bf8(kb + c * 16 * D_);
        f32x4 sacc[4];
        #pragma unroll
        for (int c = 0; c < 4; ++c)
            sacc[c] = __builtin_amdgcn_mfma_f32_16x16x32_bf16(kf[c], qf, zf, 0, 0, 0);
        __syncthreads();
        // ---- scale + mask; lane holds S^T[16c+4g+r][q=i] ----
        float p[4][4];
        float tmax = -INFINITY;
        #pragma unroll
        for (int c = 0; c < 4; ++c) {
            float4 ad = *(const float4*)&maskn[c * 16 + g * 4];
            p[c][0] = fmaf(sacc[c][0], scale, ad.x);
            p[c][1] = fmaf(sacc[c][1], scale, ad.y);
            p[c][2] = fmaf(sacc[c][2], scale, ad.z);
            p[c][3] = fmaf(sacc[c][3], scale, ad.w);
            tmax = fmaxf(tmax, fmaxf(fmaxf(p[c][0], p[c][1]), fmaxf(p[c][2], p[c][3])));
        }
        tmax = fmaxf(tmax, __shfl_xor(tmax, 16));
        tmax = fmaxf(tmax, __shfl_xor(tmax, 32));
        float mn  = fmaxf(m, tmax);
        float fac = __expf(m - mn);
        float psum = 0.f;
        #pragma unroll
        for (int c = 0; c < 4; ++c) {
            p[c][0] = __expf(p[c][0] - mn); p[c][1] = __expf(p[c][1] - mn);
            p[c][2] = __expf(p[c][2] - mn); p[c][3] = __expf(p[c][3] - mn);
            psum += (p[c][0] + p[c][1]) + (p[c][2] + p[c][3]);
        }
        psum += __shfl_xor(psum, 16);
        psum += __shfl_xor(psum, 32);
        l = l * fac + psum;
        m = mn;
        cacc[0] *= fac;
        cacc[1] *= fac;
        // ---- pack P^T to bf16 words: wrd[c][w] = (P[16c+4g+2w], P[16c+4g+2w+1]) ----
        unsigned int wrd[4][2];
        #pragma unroll
        for (int c = 0; c < 4; ++c) {
            wrd[c][0] = pk2(p[c][0], p[c][1]);
            wrd[c][1] = pk2(p[c][2], p[c][3]);
        }
        // ---- PV: ctx^T += V-frag x P^T-frag ----
        #pragma unroll
        for (int kc = 0; kc < 2; ++kc) {
            u32x4 bw;
            #pragma unroll
            for (int j2 = 0; j2 < 4; ++j2) {
                int src = ((2 * (g & 1) + (j2 >> 1)) << 4) + i;
                unsigned int lo = (unsigned int)__shfl((int)wrd[2 * kc][j2 & 1], src);
                unsigned int hi = (unsigned int)__shfl((int)wrd[2 * kc + 1][j2 & 1], src);
                bw[j2] = (g >= 2) ? hi : lo;
            }
            short8 pf = __builtin_bit_cast(short8, bw);
            #pragma unroll
            for (int vh = 0; vh < 2; ++vh) {
                const unsigned int* vp = &Vp[(kc * 16 + g * 4) * 36 + vh * 16 + i];
                u32x4 vw;
                vw[0] = vp[0]; vw[1] = vp[36]; vw[2] = vp[72]; vw[3] = vp[108];
                short8 vf = __builtin_bit_cast(short8, vw);
                cacc[vh] = __builtin_amdgcn_mfma_f32_16x16x32_bf16(vf, pf, cacc[vh], 0, 0, 0);
            }
        }
        __syncthreads();
    }
    // lane holds ctx^T[v = vh*16+4g+r][q=i]
    const float inv = 1.f / l;
    float* crow = ctxo + (bS + q0 + wid * 16 + i) * D_ + h * 32;
    #pragma unroll
    for (int vh = 0; vh < 2; ++vh)
        #pragma unroll
        for (int r = 0; r < 4; ++r)
            crow[vh * 16 + g * 4 + r] = cacc[vh][r] * inv;
}

// ---------------- classifier head (tiny; one block) ----------------
__global__ __launch_bounds__(256) void head_kernel(
    const float* __restrict__ X,
    const float* __restrict__ ft1w, const float* __restrict__ ft1b,
    const float* __restrict__ ft2w, const float* __restrict__ ft2b,
    const float* __restrict__ clw,  const float* __restrict__ clb,
    float* __restrict__ out)
{
    __shared__ float clsS[8][256];
    __shared__ float h1S[8][256];
    __shared__ float featS[8][128];
    const int t = threadIdx.x;
    #pragma unroll
    for (int j = 0; j < 8; ++j) {
        int idx = t + j * 256;
        int b = idx >> 8, d = idx & 255;
        clsS[b][d] = X[(size_t)b * S_ * D_ + d];
    }
    __syncthreads();
    {
        float s[8] = {};
        for (int d = 0; d < 256; ++d) {
            float w = ft1w[d * 256 + t];
            #pragma unroll
            for (int b = 0; b < 8; ++b) s[b] = fmaf(clsS[b][d], w, s[b]);
        }
        float bias = ft1b[t];
        #pragma unroll
        for (int b = 0; b < 8; ++b) h1S[b][t] = fmaxf(s[b] + bias, 0.f);
    }
    __syncthreads();
    #pragma unroll
    for (int j = 0; j < 4; ++j) {
        int idx = t + j * 256;           // b*128 + c
        int b = idx >> 7, c = idx & 127;
        float s = 0.f;
        for (int d = 0; d < 256; ++d) s = fmaf(h1S[b][d], ft2w[d * 128 + c], s);
        s += ft2b[c];
        featS[b][c] = s;
        out[16 + idx] = s;
    }
    __syncthreads();
    if (t < 16) {
        int b = t >> 1, c = t & 1;
        float s = 0.f;
        for (int d = 0; d < 128; ++d) s = fmaf(featS[b][d], clw[d * 2 + c], s);
        out[t] = s + clb[c];
    }
}

extern "C" void kernel_launch(void* const* d_in, const int* in_sizes, int n_in,
                              void* d_out, int out_size, void* d_ws, size_t ws_size,
                              hipStream_t stream)
{
    const int*   ids  = (const int*)d_in[0];
    const float* tok  = (const float*)d_in[1];
    const float* pos  = (const float*)d_in[2];
    const float* elnw = (const float*)d_in[3];
    const float* elnb = (const float*)d_in[4];
    const float* Wq   = (const float*)d_in[5];
    const float* bq   = (const float*)d_in[6];
    const float* Wk   = (const float*)d_in[7];
    const float* bk   = (const float*)d_in[8];
    const float* Wv   = (const float*)d_in[9];
    const float* bv   = (const float*)d_in[10];
    const float* Wo   = (const float*)d_in[11];
    const float* bo   = (const float*)d_in[12];
    const float* lnw  = (const float*)d_in[13];
    const float* lnb  = (const float*)d_in[14];
    const float* W1   = (const float*)d_in[15];
    const float* b1   = (const float*)d_in[16];
    const float* W2   = (const float*)d_in[17];
    const float* b2   = (const float*)d_in[18];
    const float* ft1w = (const float*)d_in[19];
    const float* ft1b = (const float*)d_in[20];
    const float* ft2w = (const float*)d_in[21];
    const float* ft2b = (const float*)d_in[22];
    const float* clw  = (const float*)d_in[23];
    const float* clb  = (const float*)d_in[24];
    float* out = (float*)d_out;

    char* ws = (char*)d_ws;
    const size_t SZ = (size_t)8192 * 256 * 4;       // one (B*S, D) f32 buffer
    float* X   = (float*)(ws + 0 * SZ);
    float* Y   = (float*)(ws + 1 * SZ);
    float* T   = (float*)(ws + 2 * SZ);
    float* q   = (float*)(ws + 3 * SZ);
    float* k   = (float*)(ws + 4 * SZ);
    float* v   = (float*)(ws + 5 * SZ);
    float* ctx = (float*)(ws + 6 * SZ);
    float* Hb  = (float*)(ws + 3 * SZ);             // overlaps dead q/k/v

    embed_ln_kernel<<<8192, 64, 0, stream>>>(ids, tok, pos, elnw, elnb, X);

    for (int i = 0; i < 4; ++i) {
        const float* Wq_i = Wq + i * 65536;  const float* bq_i = bq + i * 256;
        const float* Wk_i = Wk + i * 65536;  const float* bk_i = bk + i * 256;
        const float* Wv_i = Wv + i * 65536;  const float* bv_i = bv + i * 256;
        const float* Wo_i = Wo + i * 65536;  const float* bo_i = bo + i * 256;

        gemm_qkv_kernel<<<dim3(64, 12), 256, 0, stream>>>(
            X, Wq_i, Wk_i, Wv_i, bq_i, bk_i, bv_i, q, k, v);
        attn_mfma_kernel<<<dim3(64, 16), 256, 0, stream>>>(q, k, v, ids, ctx);
        gemm_kernel<4, 0><<<dim3(128, 4), 256, 0, stream>>>(ctx, Wo_i, bo_i, Y, 256, 256);
        ln_res_kernel<<<8192, 64, 0, stream>>>(Y, X, lnw + i * 256, lnb + i * 256, T);
        gemm_kernel<8, 1><<<dim3(64, 16), 256, 0, stream>>>(T, W1 + i * 262144, b1 + i * 1024, Hb, 1024, 256);
        gemm_kernel<4, 0><<<dim3(128, 4), 256, 0, stream>>>(Hb, W2 + i * 262144, b2 + i * 256, X, 256, 1024);
    }

    head_kernel<<<1, 256, 0, stream>>>(X, ft1w, ft1b, ft2w, ft2b, clw, clb, out);
}

// Round 3
// 477.890 us; speedup vs baseline: 10.4605x; 2.2413x over previous
//
#include <hip/hip_runtime.h>
#include <math.h>

#define S_ 1024
#define D_ 256

typedef __attribute__((ext_vector_type(8))) _Float16 half8;
typedef __attribute__((ext_vector_type(4))) _Float16 half4;
typedef __attribute__((ext_vector_type(4))) float f32x4;
typedef __attribute__((ext_vector_type(4))) unsigned int u32x4;

__device__ __forceinline__ float wave_sum64(float x) {
    x += __shfl_xor(x, 32); x += __shfl_xor(x, 16); x += __shfl_xor(x, 8);
    x += __shfl_xor(x, 4);  x += __shfl_xor(x, 2);  x += __shfl_xor(x, 1);
    return x;
}

__device__ __forceinline__ unsigned int pk2h(float lo, float hi) {
    unsigned short a = __builtin_bit_cast(unsigned short, (_Float16)lo);
    unsigned short b = __builtin_bit_cast(unsigned short, (_Float16)hi);
    return (unsigned int)a | ((unsigned int)b << 16);
}

#define GLD16(gp, lp) __builtin_amdgcn_global_load_lds( \
    (const __attribute__((address_space(1))) void*)(gp), \
    (__attribute__((address_space(3))) void*)(lp), 16, 0, 0)

// ---------------- weight prep: transpose + fp16 convert ----------------
// generic: src f32 [K][N] (layer stride K*N) -> dst fp16 [N][K]
__global__ __launch_bounds__(256) void transpose_cvt(
    const float* __restrict__ src, _Float16* __restrict__ dst, int K, int N)
{
    __shared__ float tile[32][33];
    src += (size_t)blockIdx.z * K * N;
    dst += (size_t)blockIdx.z * K * N;
    const int bx = blockIdx.x * 32;   // n
    const int by = blockIdx.y * 32;   // k
    const int t = threadIdx.x;
    const int c = t & 31, r0 = t >> 5;
    #pragma unroll
    for (int j = 0; j < 4; ++j)
        tile[r0 + 8 * j][c] = src[(size_t)(by + r0 + 8 * j) * N + bx + c];
    __syncthreads();
    #pragma unroll
    for (int j = 0; j < 4; ++j)
        dst[(size_t)(bx + r0 + 8 * j) * K + by + c] = (_Float16)tile[c][r0 + 8 * j];
}

// qkv: Wq/Wk/Wv f32 [256][256] per layer -> qkvT fp16 [L][768][256]
__global__ __launch_bounds__(256) void transpose_qkv(
    const float* __restrict__ Wq, const float* __restrict__ Wk,
    const float* __restrict__ Wv, _Float16* __restrict__ qkvT)
{
    __shared__ float tile[32][33];
    const int z = blockIdx.z, l = z / 3, m = z % 3;
    const float* src = (m == 0 ? Wq : (m == 1 ? Wk : Wv)) + (size_t)l * 65536;
    _Float16* dst = qkvT + (size_t)l * 196608 + (size_t)m * 65536;
    const int bx = blockIdx.x * 32;   // n
    const int by = blockIdx.y * 32;   // k
    const int t = threadIdx.x;
    const int c = t & 31, r0 = t >> 5;
    #pragma unroll
    for (int j = 0; j < 4; ++j)
        tile[r0 + 8 * j][c] = src[(size_t)(by + r0 + 8 * j) * 256 + bx + c];
    __syncthreads();
    #pragma unroll
    for (int j = 0; j < 4; ++j)
        dst[(size_t)(bx + r0 + 8 * j) * 256 + by + c] = (_Float16)tile[c][r0 + 8 * j];
}

__global__ __launch_bounds__(256) void pack_bias(
    const float* __restrict__ bq, const float* __restrict__ bk,
    const float* __restrict__ bv, float* __restrict__ bqkv)
{
    const int z = blockIdx.x, l = z / 3, m = z % 3;
    const float* s = (m == 0 ? bq : (m == 1 ? bk : bv)) + l * 256;
    bqkv[l * 768 + m * 256 + threadIdx.x] = s[threadIdx.x];
}

// ---------------- embed + LN; writes f32 X and fp16 Xh ----------------
__global__ __launch_bounds__(64) void embed_ln_kernel(
    const int* __restrict__ ids, const float* __restrict__ tok,
    const float* __restrict__ pos, const float* __restrict__ w,
    const float* __restrict__ b, float* __restrict__ X, _Float16* __restrict__ Xh)
{
    const int tokid = blockIdx.x;
    const int s = tokid & (S_ - 1);
    const int t = threadIdx.x;
    const int id = ids[tokid];
    float4 e = *(const float4*)&tok[id * D_ + t * 4];
    float4 p = *(const float4*)&pos[s * D_ + t * 4];
    float4 x = make_float4(e.x + p.x, e.y + p.y, e.z + p.z, e.w + p.w);
    float sum = x.x + x.y + x.z + x.w;
    float sq  = x.x * x.x + x.y * x.y + x.z * x.z + x.w * x.w;
    sum = wave_sum64(sum); sq = wave_sum64(sq);
    float mean = sum * (1.f / D_);
    float var  = sq * (1.f / D_) - mean * mean;
    float rs   = rsqrtf(var + 1e-5f);
    float4 wv = *(const float4*)&w[t * 4];
    float4 bv = *(const float4*)&b[t * 4];
    float4 o = make_float4((x.x - mean) * rs * wv.x + bv.x,
                           (x.y - mean) * rs * wv.y + bv.y,
                           (x.z - mean) * rs * wv.z + bv.z,
                           (x.w - mean) * rs * wv.w + bv.w);
    *(float4*)&X[(size_t)tokid * D_ + t * 4] = o;
    half4 oh = { (_Float16)o.x, (_Float16)o.y, (_Float16)o.z, (_Float16)o.w };
    *(half4*)&Xh[(size_t)tokid * D_ + t * 4] = oh;
}

// ---------------- residual add + LN -> fp16 T ----------------
__global__ __launch_bounds__(64) void ln_res_kernel(
    const float* __restrict__ Y, const float* __restrict__ R,
    const float* __restrict__ w, const float* __restrict__ b,
    _Float16* __restrict__ Th)
{
    const int tokid = blockIdx.x;
    const int t = threadIdx.x;
    const size_t base = (size_t)tokid * D_ + t * 4;
    float4 y = *(const float4*)&Y[base];
    float4 r = *(const float4*)&R[base];
    float4 x = make_float4(y.x + r.x, y.y + r.y, y.z + r.z, y.w + r.w);
    float sum = x.x + x.y + x.z + x.w;
    float sq  = x.x * x.x + x.y * x.y + x.z * x.z + x.w * x.w;
    sum = wave_sum64(sum); sq = wave_sum64(sq);
    float mean = sum * (1.f / D_);
    float var  = sq * (1.f / D_) - mean * mean;
    float rs   = rsqrtf(var + 1e-5f);
    float4 wv = *(const float4*)&w[t * 4];
    float4 bv = *(const float4*)&b[t * 4];
    half4 oh = { (_Float16)((x.x - mean) * rs * wv.x + bv.x),
                 (_Float16)((x.y - mean) * rs * wv.y + bv.y),
                 (_Float16)((x.z - mean) * rs * wv.z + bv.z),
                 (_Float16)((x.w - mean) * rs * wv.w + bv.w) };
    *(half4*)&Th[base] = oh;
}

// ---------------- fp16 MFMA GEMM: C = A(M x K) @ Bt^T + bias ----------------
// A fp16 [M][K]; Bt fp16 [N][K]; bias f32 [N].
// BM=128, BN=64, BK=64; 256 thr = 4 waves (2x2); wave tile 64x32.
// MODE: 0 = f32 out; 1 = fp16 out + relu; 2 = f32 + fp16 out; 3 = fp16 out.
template<int MODE>
__global__ __launch_bounds__(256) void gemm_f16(
    const _Float16* __restrict__ A, const _Float16* __restrict__ Bt,
    const float* __restrict__ bias,
    float* __restrict__ Cf, _Float16* __restrict__ Ch,
    int K, int N)
{
    __shared__ _Float16 As[2][8192];    // [128][64], source-swizzled
    const int t = threadIdx.x;
    const int wid = t >> 6, lane = t & 63;
    const int wr = wid >> 1, wc = wid & 1;
    const int m0 = blockIdx.x * 128, n0 = blockIdx.y * 64;
    const int li = lane & 15, lg = lane >> 4;
    const int srow = lane >> 3;                 // staging row-in-chunk 0..7
    const int scg = (lane & 7) ^ srow;          // swizzled source col-group

    f32x4 acc[4][2];
    const f32x4 zf = {0.f, 0.f, 0.f, 0.f};
    #pragma unroll
    for (int mr = 0; mr < 4; ++mr) { acc[mr][0] = zf; acc[mr][1] = zf; }

    const int KT = K >> 6;
    // prologue stage of k-tile 0 into buffer 0
    {
        const _Float16* Ab = A + (size_t)m0 * K;
        #pragma unroll
        for (int j = 0; j < 4; ++j) {
            int row = (wid * 4 + j) * 8 + srow;
            GLD16(Ab + (size_t)row * K + scg * 8, &As[0][(wid * 4 + j) * 512]);
        }
    }
    __syncthreads();

    for (int kt = 0; kt < KT; ++kt) {
        const int cur = kt & 1;
        if (kt + 1 < KT) {
            const _Float16* Ab = A + (size_t)m0 * K + (kt + 1) * 64;
            #pragma unroll
            for (int j = 0; j < 4; ++j) {
                int row = (wid * 4 + j) * 8 + srow;
                GLD16(Ab + (size_t)row * K + scg * 8, &As[cur ^ 1][(wid * 4 + j) * 512]);
            }
        }
        // B fragments straight from global (L1/L2-hot weights)
        half8 bfr[2][2];
        #pragma unroll
        for (int nr = 0; nr < 2; ++nr) {
            const _Float16* bp = Bt + (size_t)(n0 + wc * 32 + nr * 16 + li) * K + kt * 64 + lg * 8;
            bfr[nr][0] = *(const half8*)bp;
            bfr[nr][1] = *(const half8*)(bp + 32);
        }
        #pragma unroll
        for (int kk = 0; kk < 2; ++kk) {
            half8 af[4];
            #pragma unroll
            for (int mr = 0; mr < 4; ++mr) {
                int arow = wr * 64 + mr * 16 + li;
                int ablk = (kk * 4 + lg) ^ (li & 7);
                af[mr] = *(const half8*)&As[cur][arow * 64 + ablk * 8];
            }
            #pragma unroll
            for (int mr = 0; mr < 4; ++mr)
                #pragma unroll
                for (int nr = 0; nr < 2; ++nr)
                    acc[mr][nr] = __builtin_amdgcn_mfma_f32_16x16x32_f16(
                        af[mr], bfr[nr][kk], acc[mr][nr], 0, 0, 0);
        }
        __syncthreads();
    }

    #pragma unroll
    for (int nr = 0; nr < 2; ++nr) {
        const int n = n0 + wc * 32 + nr * 16 + li;
        const float bv = bias[n];
        #pragma unroll
        for (int mr = 0; mr < 4; ++mr) {
            #pragma unroll
            for (int r = 0; r < 4; ++r) {
                const int m = m0 + wr * 64 + mr * 16 + lg * 4 + r;
                float o = acc[mr][nr][r] + bv;
                if (MODE == 1) o = fmaxf(o, 0.f);
                if (MODE == 0 || MODE == 2) Cf[(size_t)m * N + n] = o;
                if (MODE != 0) Ch[(size_t)m * N + n] = (_Float16)o;
            }
        }
    }
}

// ---------------- fp16 MFMA flash attention ----------------
// qkv packed [B*S][768]: q 0..255, k 256..511, v 512..767. ctx out fp16 [B*S][256].
__global__ __launch_bounds__(256, 4) void attn_f16_kernel(
    const _Float16* __restrict__ qkv, const int* __restrict__ ids,
    _Float16* __restrict__ ctxo)
{
    __shared__ unsigned int Vp[32 * 36];
    __shared__ float maskn[64];
    const int t = threadIdx.x;
    const int bh = blockIdx.x, b = bh >> 3, h = bh & 7;
    const int q0 = blockIdx.y * 64;
    const int wid = t >> 6;
    const int lane = t & 63;
    const int i = lane & 15;
    const int g = lane >> 4;
    const int kp = t >> 3;
    const int v0s = (t & 7) * 4;

    const size_t bS = (size_t)b * S_;
    const float scale = 0.17677669529663687f;

    const half8 qf = *(const half8*)(qkv + (bS + q0 + wid * 16 + i) * 768 + h * 32 + g * 8);

    float m = -INFINITY, l = 0.f;
    f32x4 cacc[2];
    const f32x4 zf = {0.f, 0.f, 0.f, 0.f};
    cacc[0] = zf; cacc[1] = zf;

    const _Float16* kbase = qkv + 256 + (bS + i) * 768 + h * 32 + g * 8;
    const _Float16* vbase = qkv + 512 + (bS + 2 * kp) * 768 + h * 32 + v0s;

    for (int kt = 0; kt < 16; ++kt) {
        const int k0 = kt * 64;
        // ---- stage V fp16-pairs + mask ----
        {
            const ushort* vb = (const ushort*)(vbase + (size_t)k0 * 768);
            ushort4 a0 = *(const ushort4*)vb;
            ushort4 a1 = *(const ushort4*)(vb + 768);
            u32x4 wv;
            wv[0] = (unsigned)a0.x | ((unsigned)a1.x << 16);
            wv[1] = (unsigned)a0.y | ((unsigned)a1.y << 16);
            wv[2] = (unsigned)a0.z | ((unsigned)a1.z << 16);
            wv[3] = (unsigned)a0.w | ((unsigned)a1.w << 16);
            *(u32x4*)&Vp[kp * 36 + v0s] = wv;
            if (t < 64) maskn[t] = (ids[bS + k0 + t] == 0) ? -1e9f : 0.f;
        }
        // ---- K fragments + S^T MFMAs ----
        half8 kf[4];
        const _Float16* kb = kbase + (size_t)k0 * 768;
        #pragma unroll
        for (int c = 0; c < 4; ++c) kf[c] = *(const half8*)(kb + c * 16 * 768);
        f32x4 sacc[4];
        #pragma unroll
        for (int c = 0; c < 4; ++c)
            sacc[c] = __builtin_amdgcn_mfma_f32_16x16x32_f16(kf[c], qf, zf, 0, 0, 0);
        __syncthreads();
        // ---- scale + mask; lane holds S^T[16c+4g+r][q=i] ----
        float p[4][4];
        float tmax = -INFINITY;
        #pragma unroll
        for (int c = 0; c < 4; ++c) {
            float4 ad = *(const float4*)&maskn[c * 16 + g * 4];
            p[c][0] = fmaf(sacc[c][0], scale, ad.x);
            p[c][1] = fmaf(sacc[c][1], scale, ad.y);
            p[c][2] = fmaf(sacc[c][2], scale, ad.z);
            p[c][3] = fmaf(sacc[c][3], scale, ad.w);
            tmax = fmaxf(tmax, fmaxf(fmaxf(p[c][0], p[c][1]), fmaxf(p[c][2], p[c][3])));
        }
        tmax = fmaxf(tmax, __shfl_xor(tmax, 16));
        tmax = fmaxf(tmax, __shfl_xor(tmax, 32));
        float mn  = fmaxf(m, tmax);
        float fac = __expf(m - mn);
        float psum = 0.f;
        #pragma unroll
        for (int c = 0; c < 4; ++c) {
            p[c][0] = __expf(p[c][0] - mn); p[c][1] = __expf(p[c][1] - mn);
            p[c][2] = __expf(p[c][2] - mn); p[c][3] = __expf(p[c][3] - mn);
            psum += (p[c][0] + p[c][1]) + (p[c][2] + p[c][3]);
        }
        psum += __shfl_xor(psum, 16);
        psum += __shfl_xor(psum, 32);
        l = l * fac + psum;
        m = mn;
        cacc[0] *= fac;
        cacc[1] *= fac;
        // ---- pack P^T to fp16 words ----
        unsigned int wrd[4][2];
        #pragma unroll
        for (int c = 0; c < 4; ++c) {
            wrd[c][0] = pk2h(p[c][0], p[c][1]);
            wrd[c][1] = pk2h(p[c][2], p[c][3]);
        }
        // ---- PV: ctx^T += V-frag x P^T-frag ----
        #pragma unroll
        for (int kc = 0; kc < 2; ++kc) {
            u32x4 bw;
            #pragma unroll
            for (int j2 = 0; j2 < 4; ++j2) {
                int src = ((2 * (g & 1) + (j2 >> 1)) << 4) + i;
                unsigned int lo = (unsigned int)__shfl((int)wrd[2 * kc][j2 & 1], src);
                unsigned int hi = (unsigned int)__shfl((int)wrd[2 * kc + 1][j2 & 1], src);
                bw[j2] = (g >= 2) ? hi : lo;
            }
            half8 pf = __builtin_bit_cast(half8, bw);
            #pragma unroll
            for (int vh = 0; vh < 2; ++vh) {
                const unsigned int* vp = &Vp[(kc * 16 + g * 4) * 36 + vh * 16 + i];
                u32x4 vw;
                vw[0] = vp[0]; vw[1] = vp[36]; vw[2] = vp[72]; vw[3] = vp[108];
                half8 vf = __builtin_bit_cast(half8, vw);
                cacc[vh] = __builtin_amdgcn_mfma_f32_16x16x32_f16(vf, pf, cacc[vh], 0, 0, 0);
            }
        }
        __syncthreads();
    }
    const float inv = 1.f / l;
    _Float16* crow = ctxo + (bS + q0 + wid * 16 + i) * 256 + h * 32;
    #pragma unroll
    for (int vh = 0; vh < 2; ++vh) {
        half4 st;
        #pragma unroll
        for (int r = 0; r < 4; ++r) st[r] = (_Float16)(cacc[vh][r] * inv);
        *(half4*)&crow[vh * 16 + g * 4] = st;
    }
}

// ---------------- classifier head (f32, one block) ----------------
__global__ __launch_bounds__(256) void head_kernel(
    const float* __restrict__ X,
    const float* __restrict__ ft1w, const float* __restrict__ ft1b,
    const float* __restrict__ ft2w, const float* __restrict__ ft2b,
    const float* __restrict__ clw,  const float* __restrict__ clb,
    float* __restrict__ out)
{
    __shared__ float clsS[8][256];
    __shared__ float h1S[8][256];
    __shared__ float featS[8][128];
    const int t = threadIdx.x;
    #pragma unroll
    for (int j = 0; j < 8; ++j) {
        int idx = t + j * 256;
        int b = idx >> 8, d = idx & 255;
        clsS[b][d] = X[(size_t)b * S_ * D_ + d];
    }
    __syncthreads();
    {
        float s[8] = {};
        for (int d = 0; d < 256; ++d) {
            float w = ft1w[d * 256 + t];
            #pragma unroll
            for (int b = 0; b < 8; ++b) s[b] = fmaf(clsS[b][d], w, s[b]);
        }
        float bias = ft1b[t];
        #pragma unroll
        for (int b = 0; b < 8; ++b) h1S[b][t] = fmaxf(s[b] + bias, 0.f);
    }
    __syncthreads();
    #pragma unroll
    for (int j = 0; j < 4; ++j) {
        int idx = t + j * 256;
        int b = idx >> 7, c = idx & 127;
        float s = 0.f;
        for (int d = 0; d < 256; ++d) s = fmaf(h1S[b][d], ft2w[d * 128 + c], s);
        s += ft2b[c];
        featS[b][c] = s;
        out[16 + idx] = s;
    }
    __syncthreads();
    if (t < 16) {
        int b = t >> 1, c = t & 1;
        float s = 0.f;
        for (int d = 0; d < 128; ++d) s = fmaf(featS[b][d], clw[d * 2 + c], s);
        out[t] = s + clb[c];
    }
}

extern "C" void kernel_launch(void* const* d_in, const int* in_sizes, int n_in,
                              void* d_out, int out_size, void* d_ws, size_t ws_size,
                              hipStream_t stream)
{
    const int*   ids  = (const int*)d_in[0];
    const float* tok  = (const float*)d_in[1];
    const float* pos  = (const float*)d_in[2];
    const float* elnw = (const float*)d_in[3];
    const float* elnb = (const float*)d_in[4];
    const float* Wq   = (const float*)d_in[5];
    const float* bq   = (const float*)d_in[6];
    const float* Wk   = (const float*)d_in[7];
    const float* bk   = (const float*)d_in[8];
    const float* Wv   = (const float*)d_in[9];
    const float* bv   = (const float*)d_in[10];
    const float* Wo   = (const float*)d_in[11];
    const float* bo   = (const float*)d_in[12];
    const float* lnw  = (const float*)d_in[13];
    const float* lnb  = (const float*)d_in[14];
    const float* W1   = (const float*)d_in[15];
    const float* b1   = (const float*)d_in[16];
    const float* W2   = (const float*)d_in[17];
    const float* b2   = (const float*)d_in[18];
    const float* ft1w = (const float*)d_in[19];
    const float* ft1b = (const float*)d_in[20];
    const float* ft2w = (const float*)d_in[21];
    const float* ft2b = (const float*)d_in[22];
    const float* clw  = (const float*)d_in[23];
    const float* clb  = (const float*)d_in[24];
    float* out = (float*)d_out;

    char* ws = (char*)d_ws;
    float*    X    = (float*)(ws);                          // 8 MB
    float*    Y    = (float*)(ws + (8ull << 20));           // 8 MB
    _Float16* Xh   = (_Float16*)(ws + (16ull << 20));       // 4 MB
    _Float16* Th   = (_Float16*)(ws + (20ull << 20));       // 4 MB
    _Float16* qkvb = (_Float16*)(ws + (24ull << 20));       // 12 MB
    _Float16* ctx  = (_Float16*)(ws + (36ull << 20));       // 4 MB
    _Float16* Hb   = (_Float16*)(ws + (24ull << 20));       // 16 MB (reuses qkv+ctx)
    _Float16* qkvT = (_Float16*)(ws + (40ull << 20));       // 1.5 MB
    _Float16* WoT  = (_Float16*)(ws + (42ull << 20));       // 0.5 MB
    _Float16* W1T  = (_Float16*)(ws + (43ull << 20));       // 2 MB
    _Float16* W2T  = (_Float16*)(ws + (45ull << 20));       // 2 MB
    float*    bqkv = (float*)(ws + (47ull << 20));          // 12 KB

    // ---- weight prep (per launch; deterministic) ----
    transpose_qkv<<<dim3(8, 8, 12), 256, 0, stream>>>(Wq, Wk, Wv, qkvT);
    transpose_cvt<<<dim3(8, 8, 4),  256, 0, stream>>>(Wo, WoT, 256, 256);
    transpose_cvt<<<dim3(32, 8, 4), 256, 0, stream>>>(W1, W1T, 256, 1024);
    transpose_cvt<<<dim3(8, 32, 4), 256, 0, stream>>>(W2, W2T, 1024, 256);
    pack_bias<<<12, 256, 0, stream>>>(bq, bk, bv, bqkv);

    embed_ln_kernel<<<8192, 64, 0, stream>>>(ids, tok, pos, elnw, elnb, X, Xh);

    for (int i = 0; i < 4; ++i) {
        gemm_f16<3><<<dim3(64, 12), 256, 0, stream>>>(
            Xh, qkvT + (size_t)i * 196608, bqkv + i * 768, nullptr, qkvb, 256, 768);
        attn_f16_kernel<<<dim3(64, 16), 256, 0, stream>>>(qkvb, ids, ctx);
        gemm_f16<0><<<dim3(64, 4), 256, 0, stream>>>(
            ctx, WoT + (size_t)i * 65536, bo + i * 256, Y, nullptr, 256, 256);
        ln_res_kernel<<<8192, 64, 0, stream>>>(Y, X, lnw + i * 256, lnb + i * 256, Th);
        gemm_f16<1><<<dim3(64, 16), 256, 0, stream>>>(
            Th, W1T + (size_t)i * 262144, b1 + i * 1024, nullptr, Hb, 256, 1024);
        gemm_f16<2><<<dim3(64, 4), 256, 0, stream>>>(
            Hb, W2T + (size_t)i * 262144, b2 + i * 256, X, Xh, 1024, 256);
    }

    head_kernel<<<1, 256, 0, stream>>>(X, ft1w, ft1b, ft2w, ft2b, clw, clb, out);
}

// Round 5
// 441.563 us; speedup vs baseline: 11.3210x; 1.0823x over previous
//
#include <hip/hip_runtime.h>
#include <math.h>

#define S_ 1024
#define D_ 256

typedef __attribute__((ext_vector_type(8))) _Float16 half8;
typedef __attribute__((ext_vector_type(4))) _Float16 half4;
typedef __attribute__((ext_vector_type(4))) float f32x4;
typedef __attribute__((ext_vector_type(4))) unsigned int u32x4;

__device__ __forceinline__ float wave_sum64(float x) {
    x += __shfl_xor(x, 32); x += __shfl_xor(x, 16); x += __shfl_xor(x, 8);
    x += __shfl_xor(x, 4);  x += __shfl_xor(x, 2);  x += __shfl_xor(x, 1);
    return x;
}

__device__ __forceinline__ unsigned int pk2h(float lo, float hi) {
    unsigned short a = __builtin_bit_cast(unsigned short, (_Float16)lo);
    unsigned short b = __builtin_bit_cast(unsigned short, (_Float16)hi);
    return (unsigned int)a | ((unsigned int)b << 16);
}

#define GLD16(gp, lp) __builtin_amdgcn_global_load_lds( \
    (const __attribute__((address_space(1))) void*)(gp), \
    (__attribute__((address_space(3))) void*)(lp), 16, 0, 0)

// ---------------- weight prep: transpose + fp16 convert ----------------
__global__ __launch_bounds__(256) void transpose_cvt(
    const float* __restrict__ src, _Float16* __restrict__ dst, int K, int N)
{
    __shared__ float tile[32][33];
    src += (size_t)blockIdx.z * K * N;
    dst += (size_t)blockIdx.z * K * N;
    const int bx = blockIdx.x * 32;   // n
    const int by = blockIdx.y * 32;   // k
    const int t = threadIdx.x;
    const int c = t & 31, r0 = t >> 5;
    #pragma unroll
    for (int j = 0; j < 4; ++j)
        tile[r0 + 8 * j][c] = src[(size_t)(by + r0 + 8 * j) * N + bx + c];
    __syncthreads();
    #pragma unroll
    for (int j = 0; j < 4; ++j)
        dst[(size_t)(bx + r0 + 8 * j) * K + by + c] = (_Float16)tile[c][r0 + 8 * j];
}

__global__ __launch_bounds__(256) void transpose_qkv(
    const float* __restrict__ Wq, const float* __restrict__ Wk,
    const float* __restrict__ Wv, _Float16* __restrict__ qkvT)
{
    __shared__ float tile[32][33];
    const int z = blockIdx.z, l = z / 3, m = z % 3;
    const float* src = (m == 0 ? Wq : (m == 1 ? Wk : Wv)) + (size_t)l * 65536;
    _Float16* dst = qkvT + (size_t)l * 196608 + (size_t)m * 65536;
    const int bx = blockIdx.x * 32;
    const int by = blockIdx.y * 32;
    const int t = threadIdx.x;
    const int c = t & 31, r0 = t >> 5;
    #pragma unroll
    for (int j = 0; j < 4; ++j)
        tile[r0 + 8 * j][c] = src[(size_t)(by + r0 + 8 * j) * 256 + bx + c];
    __syncthreads();
    #pragma unroll
    for (int j = 0; j < 4; ++j)
        dst[(size_t)(bx + r0 + 8 * j) * 256 + by + c] = (_Float16)tile[c][r0 + 8 * j];
}

__global__ __launch_bounds__(256) void pack_bias(
    const float* __restrict__ bq, const float* __restrict__ bk,
    const float* __restrict__ bv, float* __restrict__ bqkv)
{
    const int z = blockIdx.x, l = z / 3, m = z % 3;
    const float* s = (m == 0 ? bq : (m == 1 ? bk : bv)) + l * 256;
    bqkv[l * 768 + m * 256 + threadIdx.x] = s[threadIdx.x];
}

// ---------------- embed + LN (4 tokens per 256-thr block) ----------------
__global__ __launch_bounds__(256) void embed_ln_kernel(
    const int* __restrict__ ids, const float* __restrict__ tok,
    const float* __restrict__ pos, const float* __restrict__ w,
    const float* __restrict__ b, float* __restrict__ X, _Float16* __restrict__ Xh)
{
    const int wv_ = threadIdx.x >> 6, lane = threadIdx.x & 63;
    const int tokid = blockIdx.x * 4 + wv_;
    const int s = tokid & (S_ - 1);
    const int id = ids[tokid];
    float4 e = *(const float4*)&tok[id * D_ + lane * 4];
    float4 p = *(const float4*)&pos[s * D_ + lane * 4];
    float4 x = make_float4(e.x + p.x, e.y + p.y, e.z + p.z, e.w + p.w);
    float sum = x.x + x.y + x.z + x.w;
    float sq  = x.x * x.x + x.y * x.y + x.z * x.z + x.w * x.w;
    sum = wave_sum64(sum); sq = wave_sum64(sq);
    float mean = sum * (1.f / D_);
    float var  = sq * (1.f / D_) - mean * mean;
    float rs   = rsqrtf(var + 1e-5f);
    float4 wv = *(const float4*)&w[lane * 4];
    float4 bv = *(const float4*)&b[lane * 4];
    float4 o = make_float4((x.x - mean) * rs * wv.x + bv.x,
                           (x.y - mean) * rs * wv.y + bv.y,
                           (x.z - mean) * rs * wv.z + bv.z,
                           (x.w - mean) * rs * wv.w + bv.w);
    *(float4*)&X[(size_t)tokid * D_ + lane * 4] = o;
    half4 oh = { (_Float16)o.x, (_Float16)o.y, (_Float16)o.z, (_Float16)o.w };
    *(half4*)&Xh[(size_t)tokid * D_ + lane * 4] = oh;
}

// ---------------- LN (residual already added) -> fp16 ----------------
__global__ __launch_bounds__(256) void ln_kernel(
    const float* __restrict__ Y, const float* __restrict__ w,
    const float* __restrict__ b, _Float16* __restrict__ Th)
{
    const int wv_ = threadIdx.x >> 6, lane = threadIdx.x & 63;
    const int tokid = blockIdx.x * 4 + wv_;
    const size_t base = (size_t)tokid * D_ + lane * 4;
    float4 x = *(const float4*)&Y[base];
    float sum = x.x + x.y + x.z + x.w;
    float sq  = x.x * x.x + x.y * x.y + x.z * x.z + x.w * x.w;
    sum = wave_sum64(sum); sq = wave_sum64(sq);
    float mean = sum * (1.f / D_);
    float var  = sq * (1.f / D_) - mean * mean;
    float rs   = rsqrtf(var + 1e-5f);
    float4 wv = *(const float4*)&w[lane * 4];
    float4 bv = *(const float4*)&b[lane * 4];
    half4 oh = { (_Float16)((x.x - mean) * rs * wv.x + bv.x),
                 (_Float16)((x.y - mean) * rs * wv.y + bv.y),
                 (_Float16)((x.z - mean) * rs * wv.z + bv.z),
                 (_Float16)((x.w - mean) * rs * wv.w + bv.w) };
    *(half4*)&Th[base] = oh;
}

// ---------------- fp16 MFMA GEMM with counted-vmcnt pipeline ----------------
// A fp16 [M][K]; Bt fp16 [N][K]; bias f32 [N]; optional res f32 [M][N].
// BM=128, BN=64, BK=64; 256 thr = 4 waves (2x2); wave tile 64x32.
// MODE: 0=f32; 1=fp16+relu; 2=f32+fp16; 3=fp16; 4=f32 with residual add.
template<int MODE>
__global__ __launch_bounds__(256) void gemm_f16(
    const _Float16* __restrict__ A, const _Float16* __restrict__ Bt,
    const float* __restrict__ bias, const float* __restrict__ res,
    float* __restrict__ Cf, _Float16* __restrict__ Ch,
    int K, int N)
{
    __shared__ _Float16 As[2][8192];    // [128][64], source-swizzled
    const int t = threadIdx.x;
    const int wid = t >> 6, lane = t & 63;
    const int wr = wid >> 1, wc = wid & 1;
    const int m0 = blockIdx.x * 128, n0 = blockIdx.y * 64;
    const int li = lane & 15, lg = lane >> 4;
    const int srow = lane >> 3;
    const int scg = (lane & 7) ^ srow;

    f32x4 acc[4][2];
    const f32x4 zf = {0.f, 0.f, 0.f, 0.f};
    #pragma unroll
    for (int mr = 0; mr < 4; ++mr) { acc[mr][0] = zf; acc[mr][1] = zf; }

    const int KT = K >> 6;
    // prologue stage of k-tile 0 into buffer 0
    {
        const _Float16* Ab = A + (size_t)m0 * K;
        #pragma unroll
        for (int j = 0; j < 4; ++j) {
            int row = (wid * 4 + j) * 8 + srow;
            GLD16(Ab + (size_t)row * K + scg * 8, &As[0][(wid * 4 + j) * 512]);
        }
    }

    for (int kt = 0; kt < KT; ++kt) {
        const int cur = kt & 1;
        // B fragments first (global; retire before the stage loads below)
        half8 bfr[2][2];
        #pragma unroll
        for (int nr = 0; nr < 2; ++nr) {
            const _Float16* bp = Bt + (size_t)(n0 + wc * 32 + nr * 16 + li) * K + kt * 64 + lg * 8;
            bfr[nr][0] = *(const half8*)bp;
            bfr[nr][1] = *(const half8*)(bp + 32);
        }
        // stage next tile, then wait only for the CURRENT tile (counted vmcnt)
        if (kt + 1 < KT) {
            const _Float16* Ab = A + (size_t)m0 * K + (kt + 1) * 64;
            #pragma unroll
            for (int j = 0; j < 4; ++j) {
                int row = (wid * 4 + j) * 8 + srow;
                GLD16(Ab + (size_t)row * K + scg * 8, &As[cur ^ 1][(wid * 4 + j) * 512]);
            }
            asm volatile("s_waitcnt vmcnt(8)" ::: "memory");   // allow B(4)+next-stage(4)
        } else {
            asm volatile("s_waitcnt vmcnt(4)" ::: "memory");   // allow B(4)
        }
        __builtin_amdgcn_s_barrier();
        #pragma unroll
        for (int kk = 0; kk < 2; ++kk) {
            half8 af[4];
            #pragma unroll
            for (int mr = 0; mr < 4; ++mr) {
                int arow = wr * 64 + mr * 16 + li;
                int ablk = (kk * 4 + lg) ^ (li & 7);
                af[mr] = *(const half8*)&As[cur][arow * 64 + ablk * 8];
            }
            #pragma unroll
            for (int mr = 0; mr < 4; ++mr)
                #pragma unroll
                for (int nr = 0; nr < 2; ++nr)
                    acc[mr][nr] = __builtin_amdgcn_mfma_f32_16x16x32_f16(
                        af[mr], bfr[nr][kk], acc[mr][nr], 0, 0, 0);
        }
        __builtin_amdgcn_s_barrier();   // protect buffer overwrite next iter
    }

    #pragma unroll
    for (int nr = 0; nr < 2; ++nr) {
        const int n = n0 + wc * 32 + nr * 16 + li;
        const float bv = bias[n];
        #pragma unroll
        for (int mr = 0; mr < 4; ++mr) {
            #pragma unroll
            for (int r = 0; r < 4; ++r) {
                const int m = m0 + wr * 64 + mr * 16 + lg * 4 + r;
                float o = acc[mr][nr][r] + bv;
                if (MODE == 1) o = fmaxf(o, 0.f);
                if (MODE == 4) o += res[(size_t)m * N + n];
                if (MODE == 0 || MODE == 2 || MODE == 4) Cf[(size_t)m * N + n] = o;
                if (MODE == 1 || MODE == 2 || MODE == 3) Ch[(size_t)m * N + n] = (_Float16)o;
            }
        }
    }
}

// ---------------- fp16 MFMA flash attention ----------------
__global__ __launch_bounds__(256, 4) void attn_f16_kernel(
    const _Float16* __restrict__ qkv, const int* __restrict__ ids,
    _Float16* __restrict__ ctxo)
{
    __shared__ unsigned int Vp[32 * 36];
    __shared__ float maskn[64];
    const int t = threadIdx.x;
    const int bh = blockIdx.x, b = bh >> 3, h = bh & 7;
    const int q0 = blockIdx.y * 64;
    const int wid = t >> 6;
    const int lane = t & 63;
    const int i = lane & 15;
    const int g = lane >> 4;
    const int kp = t >> 3;
    const int v0s = (t & 7) * 4;

    const size_t bS = (size_t)b * S_;
    const float scale = 0.17677669529663687f;

    const half8 qf = *(const half8*)(qkv + (bS + q0 + wid * 16 + i) * 768 + h * 32 + g * 8);

    float m = -INFINITY, l = 0.f;
    f32x4 cacc[2];
    const f32x4 zf = {0.f, 0.f, 0.f, 0.f};
    cacc[0] = zf; cacc[1] = zf;

    const _Float16* kbase = qkv + 256 + (bS + i) * 768 + h * 32 + g * 8;
    const _Float16* vbase = qkv + 512 + (bS + 2 * kp) * 768 + h * 32 + v0s;

    for (int kt = 0; kt < 16; ++kt) {
        const int k0 = kt * 64;
        {
            const ushort* vb = (const ushort*)(vbase + (size_t)k0 * 768);
            ushort4 a0 = *(const ushort4*)vb;
            ushort4 a1 = *(const ushort4*)(vb + 768);
            u32x4 wv;
            wv[0] = (unsigned)a0.x | ((unsigned)a1.x << 16);
            wv[1] = (unsigned)a0.y | ((unsigned)a1.y << 16);
            wv[2] = (unsigned)a0.z | ((unsigned)a1.z << 16);
            wv[3] = (unsigned)a0.w | ((unsigned)a1.w << 16);
            *(u32x4*)&Vp[kp * 36 + v0s] = wv;
            if (t < 64) maskn[t] = (ids[bS + k0 + t] == 0) ? -1e9f : 0.f;
        }
        half8 kf[4];
        const _Float16* kb = kbase + (size_t)k0 * 768;
        #pragma unroll
        for (int c = 0; c < 4; ++c) kf[c] = *(const half8*)(kb + c * 16 * 768);
        f32x4 sacc[4];
        #pragma unroll
        for (int c = 0; c < 4; ++c)
            sacc[c] = __builtin_amdgcn_mfma_f32_16x16x32_f16(kf[c], qf, zf, 0, 0, 0);
        __syncthreads();
        float p[4][4];
        float tmax = -INFINITY;
        #pragma unroll
        for (int c = 0; c < 4; ++c) {
            float4 ad = *(const float4*)&maskn[c * 16 + g * 4];
            p[c][0] = fmaf(sacc[c][0], scale, ad.x);
            p[c][1] = fmaf(sacc[c][1], scale, ad.y);
            p[c][2] = fmaf(sacc[c][2], scale, ad.z);
            p[c][3] = fmaf(sacc[c][3], scale, ad.w);
            tmax = fmaxf(tmax, fmaxf(fmaxf(p[c][0], p[c][1]), fmaxf(p[c][2], p[c][3])));
        }
        tmax = fmaxf(tmax, __shfl_xor(tmax, 16));
        tmax = fmaxf(tmax, __shfl_xor(tmax, 32));
        float mn  = fmaxf(m, tmax);
        float fac = __expf(m - mn);
        float psum = 0.f;
        #pragma unroll
        for (int c = 0; c < 4; ++c) {
            p[c][0] = __expf(p[c][0] - mn); p[c][1] = __expf(p[c][1] - mn);
            p[c][2] = __expf(p[c][2] - mn); p[c][3] = __expf(p[c][3] - mn);
            psum += (p[c][0] + p[c][1]) + (p[c][2] + p[c][3]);
        }
        psum += __shfl_xor(psum, 16);
        psum += __shfl_xor(psum, 32);
        l = l * fac + psum;
        m = mn;
        cacc[0] *= fac;
        cacc[1] *= fac;
        unsigned int wrd[4][2];
        #pragma unroll
        for (int c = 0; c < 4; ++c) {
            wrd[c][0] = pk2h(p[c][0], p[c][1]);
            wrd[c][1] = pk2h(p[c][2], p[c][3]);
        }
        #pragma unroll
        for (int kc = 0; kc < 2; ++kc) {
            u32x4 bw;
            #pragma unroll
            for (int j2 = 0; j2 < 4; ++j2) {
                int src = ((2 * (g & 1) + (j2 >> 1)) << 4) + i;
                unsigned int lo = (unsigned int)__shfl((int)wrd[2 * kc][j2 & 1], src);
                unsigned int hi = (unsigned int)__shfl((int)wrd[2 * kc + 1][j2 & 1], src);
                bw[j2] = (g >= 2) ? hi : lo;
            }
            half8 pf = __builtin_bit_cast(half8, bw);
            #pragma unroll
            for (int vh = 0; vh < 2; ++vh) {
                const unsigned int* vp = &Vp[(kc * 16 + g * 4) * 36 + vh * 16 + i];
                u32x4 vw;
                vw[0] = vp[0]; vw[1] = vp[36]; vw[2] = vp[72]; vw[3] = vp[108];
                half8 vfh = __builtin_bit_cast(half8, vw);
                cacc[vh] = __builtin_amdgcn_mfma_f32_16x16x32_f16(vfh, pf, cacc[vh], 0, 0, 0);
            }
        }
        __syncthreads();
    }
    const float inv = 1.f / l;
    _Float16* crow = ctxo + (bS + q0 + wid * 16 + i) * 256 + h * 32;
    #pragma unroll
    for (int vh = 0; vh < 2; ++vh) {
        half4 st;
        #pragma unroll
        for (int r = 0; r < 4; ++r) st[r] = (_Float16)(cacc[vh][r] * inv);
        *(half4*)&crow[vh * 16 + g * 4] = st;
    }
}

// ---------------- parallel classifier head ----------------
// head1: h1[8][256] = relu(cls @ ft1w + ft1b), grid 8 blocks (32 cols each)
__global__ __launch_bounds__(256) void head1_kernel(
    const float* __restrict__ X, const float* __restrict__ ft1w,
    const float* __restrict__ ft1b, float* __restrict__ h1)
{
    __shared__ float clsS[8][256];
    __shared__ float ps[8][8][32];   // [dgroup][b][n]
    const int t = threadIdx.x;
    #pragma unroll
    for (int b = 0; b < 8; ++b) clsS[b][t] = X[(size_t)b * S_ * D_ + t];
    __syncthreads();
    const int n = t & 31, dg = t >> 5;
    const int gn = blockIdx.x * 32 + n;
    float s[8] = {};
    for (int dd = 0; dd < 32; ++dd) {
        int d = dg * 32 + dd;
        float w = ft1w[d * 256 + gn];
        #pragma unroll
        for (int b = 0; b < 8; ++b) s[b] = fmaf(clsS[b][d], w, s[b]);
    }
    #pragma unroll
    for (int b = 0; b < 8; ++b) ps[dg][b][n] = s[b];
    __syncthreads();
    {
        const int b = t >> 5, nn = t & 31;
        float a = 0.f;
        #pragma unroll
        for (int g = 0; g < 8; ++g) a += ps[g][b][nn];
        const int gn2 = blockIdx.x * 32 + nn;
        h1[b * 256 + gn2] = fmaxf(a + ft1b[gn2], 0.f);
    }
}

// head2: feat[8][128] = h1 @ ft2w + ft2b; writes featW and out[16..]; grid 4
__global__ __launch_bounds__(256) void head2_kernel(
    const float* __restrict__ h1, const float* __restrict__ ft2w,
    const float* __restrict__ ft2b, float* __restrict__ featW,
    float* __restrict__ out)
{
    __shared__ float hS[8][256];
    __shared__ float ps[8][8][32];
    const int t = threadIdx.x;
    #pragma unroll
    for (int b = 0; b < 8; ++b) hS[b][t] = h1[b * 256 + t];
    __syncthreads();
    const int n = t & 31, dg = t >> 5;
    const int gn = blockIdx.x * 32 + n;
    float s[8] = {};
    for (int dd = 0; dd < 32; ++dd) {
        int d = dg * 32 + dd;
        float w = ft2w[d * 128 + gn];
        #pragma unroll
        for (int b = 0; b < 8; ++b) s[b] = fmaf(hS[b][d], w, s[b]);
    }
    #pragma unroll
    for (int b = 0; b < 8; ++b) ps[dg][b][n] = s[b];
    __syncthreads();
    {
        const int b = t >> 5, nn = t & 31;
        float a = 0.f;
        #pragma unroll
        for (int g = 0; g < 8; ++g) a += ps[g][b][nn];
        const int gn2 = blockIdx.x * 32 + nn;
        float v = a + ft2b[gn2];
        featW[b * 128 + gn2] = v;
        out[16 + b * 128 + gn2] = v;
    }
}

// head3: logits = feat @ cls_w + cls_b; 1 block
__global__ __launch_bounds__(64) void head3_kernel(
    const float* __restrict__ featW, const float* __restrict__ clw,
    const float* __restrict__ clb, float* __restrict__ out)
{
    const int t = threadIdx.x;
    if (t < 16) {
        const int b = t >> 1, c = t & 1;
        float s = 0.f;
        for (int d = 0; d < 128; ++d) s = fmaf(featW[b * 128 + d], clw[d * 2 + c], s);
        out[t] = s + clb[c];
    }
}

extern "C" void kernel_launch(void* const* d_in, const int* in_sizes, int n_in,
                              void* d_out, int out_size, void* d_ws, size_t ws_size,
                              hipStream_t stream)
{
    const int*   ids  = (const int*)d_in[0];
    const float* tok  = (const float*)d_in[1];
    const float* pos  = (const float*)d_in[2];
    const float* elnw = (const float*)d_in[3];
    const float* elnb = (const float*)d_in[4];
    const float* Wq   = (const float*)d_in[5];
    const float* bq   = (const float*)d_in[6];
    const float* Wk   = (const float*)d_in[7];
    const float* bk   = (const float*)d_in[8];
    const float* Wv   = (const float*)d_in[9];
    const float* bv   = (const float*)d_in[10];
    const float* Wo   = (const float*)d_in[11];
    const float* bo   = (const float*)d_in[12];
    const float* lnw  = (const float*)d_in[13];
    const float* lnb  = (const float*)d_in[14];
    const float* W1   = (const float*)d_in[15];
    const float* b1   = (const float*)d_in[16];
    const float* W2   = (const float*)d_in[17];
    const float* b2   = (const float*)d_in[18];
    const float* ft1w = (const float*)d_in[19];
    const float* ft1b = (const float*)d_in[20];
    const float* ft2w = (const float*)d_in[21];
    const float* ft2b = (const float*)d_in[22];
    const float* clw  = (const float*)d_in[23];
    const float* clb  = (const float*)d_in[24];
    float* out = (float*)d_out;

    char* ws = (char*)d_ws;
    float*    X    = (float*)(ws);                          // 8 MB
    float*    Y    = (float*)(ws + (8ull << 20));           // 8 MB
    _Float16* Xh   = (_Float16*)(ws + (16ull << 20));       // 4 MB
    _Float16* Th   = (_Float16*)(ws + (20ull << 20));       // 4 MB
    _Float16* qkvb = (_Float16*)(ws + (24ull << 20));       // 12 MB
    _Float16* ctx  = (_Float16*)(ws + (36ull << 20));       // 4 MB
    _Float16* Hb   = (_Float16*)(ws + (24ull << 20));       // 16 MB (reuses qkv+ctx)
    _Float16* qkvT = (_Float16*)(ws + (40ull << 20));       // 1.5 MB
    _Float16* WoT  = (_Float16*)(ws + (42ull << 20));       // 0.5 MB
    _Float16* W1T  = (_Float16*)(ws + (43ull << 20));       // 2 MB
    _Float16* W2T  = (_Float16*)(ws + (45ull << 20));       // 2 MB
    float*    bqkv = (float*)(ws + (47ull << 20));          // 12 KB
    float*    h1W  = (float*)(ws + (47ull << 20) + (16ull << 10));  // 8 KB
    float*    feW  = (float*)(ws + (47ull << 20) + (24ull << 10));  // 4 KB

    // ---- weight prep ----
    transpose_qkv<<<dim3(8, 8, 12), 256, 0, stream>>>(Wq, Wk, Wv, qkvT);
    transpose_cvt<<<dim3(8, 8, 4),  256, 0, stream>>>(Wo, WoT, 256, 256);
    transpose_cvt<<<dim3(32, 8, 4), 256, 0, stream>>>(W1, W1T, 256, 1024);
    transpose_cvt<<<dim3(8, 32, 4), 256, 0, stream>>>(W2, W2T, 1024, 256);
    pack_bias<<<12, 256, 0, stream>>>(bq, bk, bv, bqkv);

    embed_ln_kernel<<<2048, 256, 0, stream>>>(ids, tok, pos, elnw, elnb, X, Xh);

    for (int i = 0; i < 4; ++i) {
        gemm_f16<3><<<dim3(64, 12), 256, 0, stream>>>(
            Xh, qkvT + (size_t)i * 196608, bqkv + i * 768, nullptr, nullptr, qkvb, 256, 768);
        attn_f16_kernel<<<dim3(64, 16), 256, 0, stream>>>(qkvb, ids, ctx);
        gemm_f16<4><<<dim3(64, 4), 256, 0, stream>>>(
            ctx, WoT + (size_t)i * 65536, bo + i * 256, X, Y, nullptr, 256, 256);
        ln_kernel<<<2048, 256, 0, stream>>>(Y, lnw + i * 256, lnb + i * 256, Th);
        gemm_f16<1><<<dim3(64, 16), 256, 0, stream>>>(
            Th, W1T + (size_t)i * 262144, b1 + i * 1024, nullptr, nullptr, Hb, 256, 1024);
        gemm_f16<2><<<dim3(64, 4), 256, 0, stream>>>(
            Hb, W2T + (size_t)i * 262144, b2 + i * 256, nullptr, X, Xh, 1024, 256);
    }

    head1_kernel<<<8, 256, 0, stream>>>(X, ft1w, ft1b, h1W);
    head2_kernel<<<4, 256, 0, stream>>>(h1W, ft2w, ft2b, feW, out);
    head3_kernel<<<1, 64, 0, stream>>>(feW, clw, clb, out);
}